// Round 3
// baseline (635.830 us; speedup 1.0000x reference)
//
#include <hip/hip_runtime.h>
#include <hip/hip_bf16.h>

#define NF 39
#define NK 64
#define NROW (NF * NK)   // 2496

__device__ __forceinline__ float bf_lo(unsigned u) { return __uint_as_float(u << 16); }
__device__ __forceinline__ float bf_hi(unsigned u) { return __uint_as_float(u & 0xffff0000u); }

__device__ __forceinline__ unsigned f2bf(float f) {
    unsigned u = __float_as_uint(f);
    return (u + 0x7fffu + ((u >> 16) & 1u)) >> 16;   // RNE
}

__global__ __launch_bounds__(512, 4)
void deepfm_kernel(const int* __restrict__ feature,
                   const float* __restrict__ v_table,
                   const float* __restrict__ w_table,
                   const float* __restrict__ w0s,
                   const float* __restrict__ W0,
                   const float* __restrict__ b0,
                   const float* __restrict__ W1,
                   const float* __restrict__ b1,
                   const float* __restrict__ W2,
                   const float* __restrict__ b2,
                   const float* __restrict__ W3,
                   const float* __restrict__ b3,
                   float* __restrict__ out)
{
    // W0 as bf16 pairs, TRANSPOSED: [jp][row] -> lane stride 4B, conflict-free b32 reads.
    __shared__ unsigned w0_lds[5 * NROW];   // 49920 B

    for (int i = threadIdx.x; i < NROW; i += 512) {
        #pragma unroll
        for (int jp = 0; jp < 5; ++jp) {
            unsigned lo = f2bf(W0[i * 10 + 2 * jp]);
            unsigned hi = f2bf(W0[i * 10 + 2 * jp + 1]);
            w0_lds[jp * NROW + i] = lo | (hi << 16);
        }
    }
    __syncthreads();

    const int lane = threadIdx.x & 63;
    const int wave = threadIdx.x >> 6;            // 0..7
    const int s0   = blockIdx.x * 32 + wave * 4;  // 4 consecutive samples per wave

    // One coalesced load of all 39 indices per sample; lane l holds feature[s][l].
    const int lcl = (lane < NF) ? lane : (NF - 1);
    int fidx[4];
    #pragma unroll
    for (int s = 0; s < 4; ++s)
        fidx[s] = feature[(s0 + s) * NF + lcl];

    // First-order term: per-lane gather from L2-resident 4MB table, reduced later.
    float wlin[4];
    #pragma unroll
    for (int s = 0; s < 4; ++s) {
        float wv = w_table[fidx[s]];
        wlin[s] = (lane < NF) ? wv : 0.f;
    }

    float h0p[4][10];
    float sv[4], sq[4];
    #pragma unroll
    for (int s = 0; s < 4; ++s) {
        sv[s] = 0.f; sq[s] = 0.f;
        #pragma unroll
        for (int j = 0; j < 10; ++j) h0p[s][j] = 0.f;
    }

    // Main loop: bounded unroll -> 16 independent saddr gathers in flight, no spill.
    #pragma unroll 4
    for (int f = 0; f < NF; ++f) {
        float v[4];
        #pragma unroll
        for (int s = 0; s < 4; ++s) {
            const int idx = __builtin_amdgcn_readlane(fidx[s], f);  // SGPR broadcast
            v[s] = v_table[(size_t)idx * NK + lane];                // saddr, coalesced 256B
        }
        unsigned u[5];
        #pragma unroll
        for (int jp = 0; jp < 5; ++jp)
            u[jp] = w0_lds[jp * NROW + f * NK + lane];              // conflict-free b32
        #pragma unroll
        for (int s = 0; s < 4; ++s) {
            sv[s] += v[s];
            sq[s]  = fmaf(v[s], v[s], sq[s]);
            #pragma unroll
            for (int jp = 0; jp < 5; ++jp) {
                h0p[s][2 * jp]     = fmaf(v[s], bf_lo(u[jp]), h0p[s][2 * jp]);
                h0p[s][2 * jp + 1] = fmaf(v[s], bf_hi(u[jp]), h0p[s][2 * jp + 1]);
            }
        }
    }

    const float w0v = w0s[0];

    #pragma unroll
    for (int s = 0; s < 4; ++s) {
        float t = fmaf(sv[s], sv[s], -sq[s]);   // s_k^2 - sum_f v_k^2 (per lane k)
        float ln = wlin[s];
        #pragma unroll
        for (int m = 1; m < 64; m <<= 1) {
            t  += __shfl_xor(t,  m, 64);
            ln += __shfl_xor(ln, m, 64);
            #pragma unroll
            for (int j = 0; j < 10; ++j)
                h0p[s][j] += __shfl_xor(h0p[s][j], m, 64);
        }
        // tiny MLP tail (wave-uniform values, computed redundantly on all lanes)
        float h0v[10];
        #pragma unroll
        for (int j = 0; j < 10; ++j) h0v[j] = fmaxf(h0p[s][j] + b0[j], 0.f);
        float h1[5];
        #pragma unroll
        for (int p = 0; p < 5; ++p) {
            float a = b1[p];
            #pragma unroll
            for (int j = 0; j < 10; ++j) a = fmaf(h0v[j], W1[j * 5 + p], a);
            h1[p] = fmaxf(a, 0.f);
        }
        float h2[3];
        #pragma unroll
        for (int q = 0; q < 3; ++q) {
            float a = b2[q];
            #pragma unroll
            for (int p = 0; p < 5; ++p) a = fmaf(h1[p], W2[p * 3 + q], a);
            h2[q] = fmaxf(a, 0.f);
        }
        float dnn = b3[0];
        #pragma unroll
        for (int q = 0; q < 3; ++q) dnn = fmaf(h2[q], W3[q], dnn);

        if (lane == 0) out[s0 + s] = 0.5f * t + ln + w0v + dnn;
    }
}

extern "C" void kernel_launch(void* const* d_in, const int* in_sizes, int n_in,
                              void* d_out, int out_size, void* d_ws, size_t ws_size,
                              hipStream_t stream) {
    const int*   feature = (const int*)  d_in[0];
    const float* v_table = (const float*)d_in[1];
    const float* w_table = (const float*)d_in[2];
    const float* w0s     = (const float*)d_in[3];
    const float* W0      = (const float*)d_in[4];
    const float* b0      = (const float*)d_in[5];
    const float* W1      = (const float*)d_in[6];
    const float* b1      = (const float*)d_in[7];
    const float* W2      = (const float*)d_in[8];
    const float* b2      = (const float*)d_in[9];
    const float* W3      = (const float*)d_in[10];
    const float* b3      = (const float*)d_in[11];

    deepfm_kernel<<<dim3(512), dim3(512), 0, stream>>>(
        feature, v_table, w_table, w0s, W0, b0, W1, b1, W2, b2, W3, b3,
        (float*)d_out);
}

// Round 4
// 372.875 us; speedup vs baseline: 1.7052x; 1.7052x over previous
//
#include <hip/hip_runtime.h>
#include <hip/hip_bf16.h>

#define NF 39
#define NK 64
#define NROW (NF * NK)   // 2496

__device__ __forceinline__ float bf_lo(unsigned u) { return __uint_as_float(u << 16); }
__device__ __forceinline__ float bf_hi(unsigned u) { return __uint_as_float(u & 0xffff0000u); }

__device__ __forceinline__ unsigned f2bf(float f) {
    unsigned u = __float_as_uint(f);
    return (u + 0x7fffu + ((u >> 16) & 1u)) >> 16;   // RNE
}

__global__ __launch_bounds__(512, 2)
void deepfm_kernel(const int* __restrict__ feature,
                   const float* __restrict__ v_table,
                   const float* __restrict__ w_table,
                   const float* __restrict__ w0s,
                   const float* __restrict__ W0,
                   const float* __restrict__ b0,
                   const float* __restrict__ W1,
                   const float* __restrict__ b1,
                   const float* __restrict__ W2,
                   const float* __restrict__ b2,
                   const float* __restrict__ W3,
                   const float* __restrict__ b3,
                   float* __restrict__ out)
{
    // W0 as bf16 pairs, TRANSPOSED: [jp][row] -> lane stride 4B, conflict-free b32 reads.
    __shared__ unsigned w0_lds[5 * NROW];   // 49920 B

    for (int i = threadIdx.x; i < NROW; i += 512) {
        #pragma unroll
        for (int jp = 0; jp < 5; ++jp) {
            unsigned lo = f2bf(W0[i * 10 + 2 * jp]);
            unsigned hi = f2bf(W0[i * 10 + 2 * jp + 1]);
            w0_lds[jp * NROW + i] = lo | (hi << 16);
        }
    }
    __syncthreads();

    const int lane = threadIdx.x & 63;
    const int wave = threadIdx.x >> 6;            // 0..7
    const int s0   = blockIdx.x * 16 + wave * 2;  // 2 consecutive samples per wave

    // One coalesced load of all 39 indices per sample; lane l holds feature[s][l].
    const int lcl = (lane < NF) ? lane : (NF - 1);
    int fidx0 = feature[(s0 + 0) * NF + lcl];
    int fidx1 = feature[(s0 + 1) * NF + lcl];

    // First-order term: per-lane gather from cache-resident 4MB table, reduced later.
    float wl0 = w_table[fidx0];
    float wl1 = w_table[fidx1];
    wl0 = (lane < NF) ? wl0 : 0.f;
    wl1 = (lane < NF) ? wl1 : 0.f;

    float h0p[2][10];
    float sv[2], sq[2];
    #pragma unroll
    for (int s = 0; s < 2; ++s) {
        sv[s] = 0.f; sq[s] = 0.f;
        #pragma unroll
        for (int j = 0; j < 10; ++j) h0p[s][j] = 0.f;
    }

    // Main loop: bounded unroll -> 8 independent saddr gathers in flight, no spill.
    #pragma unroll 4
    for (int f = 0; f < NF; ++f) {
        const int i0 = __builtin_amdgcn_readlane(fidx0, f);   // SGPR broadcast
        const int i1 = __builtin_amdgcn_readlane(fidx1, f);
        float v0 = v_table[(size_t)i0 * NK + lane];           // saddr, coalesced 256B
        float v1 = v_table[(size_t)i1 * NK + lane];
        unsigned u[5];
        #pragma unroll
        for (int jp = 0; jp < 5; ++jp)
            u[jp] = w0_lds[jp * NROW + f * NK + lane];        // conflict-free b32

        sv[0] += v0;  sq[0] = fmaf(v0, v0, sq[0]);
        sv[1] += v1;  sq[1] = fmaf(v1, v1, sq[1]);
        #pragma unroll
        for (int jp = 0; jp < 5; ++jp) {
            float lo = bf_lo(u[jp]), hi = bf_hi(u[jp]);
            h0p[0][2 * jp]     = fmaf(v0, lo, h0p[0][2 * jp]);
            h0p[0][2 * jp + 1] = fmaf(v0, hi, h0p[0][2 * jp + 1]);
            h0p[1][2 * jp]     = fmaf(v1, lo, h0p[1][2 * jp]);
            h0p[1][2 * jp + 1] = fmaf(v1, hi, h0p[1][2 * jp + 1]);
        }
    }

    const float w0v = w0s[0];
    float wlin[2] = { wl0, wl1 };

    #pragma unroll
    for (int s = 0; s < 2; ++s) {
        float t = fmaf(sv[s], sv[s], -sq[s]);   // s_k^2 - sum_f v_k^2 (per lane k)
        float ln = wlin[s];
        #pragma unroll
        for (int m = 1; m < 64; m <<= 1) {
            t  += __shfl_xor(t,  m, 64);
            ln += __shfl_xor(ln, m, 64);
            #pragma unroll
            for (int j = 0; j < 10; ++j)
                h0p[s][j] += __shfl_xor(h0p[s][j], m, 64);
        }
        // tiny MLP tail (wave-uniform values, computed redundantly on all lanes)
        float h0v[10];
        #pragma unroll
        for (int j = 0; j < 10; ++j) h0v[j] = fmaxf(h0p[s][j] + b0[j], 0.f);
        float h1[5];
        #pragma unroll
        for (int p = 0; p < 5; ++p) {
            float a = b1[p];
            #pragma unroll
            for (int j = 0; j < 10; ++j) a = fmaf(h0v[j], W1[j * 5 + p], a);
            h1[p] = fmaxf(a, 0.f);
        }
        float h2[3];
        #pragma unroll
        for (int q = 0; q < 3; ++q) {
            float a = b2[q];
            #pragma unroll
            for (int p = 0; p < 5; ++p) a = fmaf(h1[p], W2[p * 3 + q], a);
            h2[q] = fmaxf(a, 0.f);
        }
        float dnn = b3[0];
        #pragma unroll
        for (int q = 0; q < 3; ++q) dnn = fmaf(h2[q], W3[q], dnn);

        if (lane == 0) out[s0 + s] = 0.5f * t + ln + w0v + dnn;
    }
}

extern "C" void kernel_launch(void* const* d_in, const int* in_sizes, int n_in,
                              void* d_out, int out_size, void* d_ws, size_t ws_size,
                              hipStream_t stream) {
    const int*   feature = (const int*)  d_in[0];
    const float* v_table = (const float*)d_in[1];
    const float* w_table = (const float*)d_in[2];
    const float* w0s     = (const float*)d_in[3];
    const float* W0      = (const float*)d_in[4];
    const float* b0      = (const float*)d_in[5];
    const float* W1      = (const float*)d_in[6];
    const float* b1      = (const float*)d_in[7];
    const float* W2      = (const float*)d_in[8];
    const float* b2      = (const float*)d_in[9];
    const float* W3      = (const float*)d_in[10];
    const float* b3      = (const float*)d_in[11];

    deepfm_kernel<<<dim3(1024), dim3(512), 0, stream>>>(
        feature, v_table, w_table, w0s, W0, b0, W1, b1, W2, b2, W3, b3,
        (float*)d_out);
}

// Round 5
// 52.509 us; speedup vs baseline: 12.1091x; 7.1012x over previous
//
#include <hip/hip_runtime.h>
#include <hip/hip_bf16.h>

#define NF 39
#define NK 64
#define NROW (NF * NK)   // 2496

__device__ __forceinline__ float bf_lo(unsigned u) { return __uint_as_float(u << 16); }
__device__ __forceinline__ float bf_hi(unsigned u) { return __uint_as_float(u & 0xffff0000u); }

__device__ __forceinline__ unsigned f2bf(float f) {
    unsigned u = __float_as_uint(f);
    return (u + 0x7fffu + ((u >> 16) & 1u)) >> 16;   // RNE
}

__global__ __launch_bounds__(512, 2)
void deepfm_kernel(const int* __restrict__ feature,
                   const float* __restrict__ v_table,
                   const float* __restrict__ w_table,
                   const float* __restrict__ w0s,
                   const float* __restrict__ W0,
                   const float* __restrict__ b0,
                   const float* __restrict__ W1,
                   const float* __restrict__ b1,
                   const float* __restrict__ W2,
                   const float* __restrict__ b2,
                   const float* __restrict__ W3,
                   const float* __restrict__ b3,
                   float* __restrict__ out)
{
    // W0 as bf16 pairs, TRANSPOSED [jp][row]: lane stride 4B -> conflict-free b32 reads.
    __shared__ unsigned w0_lds[5 * NROW];   // 49920 B

    for (int i = threadIdx.x; i < NROW; i += 512) {
        #pragma unroll
        for (int jp = 0; jp < 5; ++jp) {
            unsigned lo = f2bf(W0[i * 10 + 2 * jp]);
            unsigned hi = f2bf(W0[i * 10 + 2 * jp + 1]);
            w0_lds[jp * NROW + i] = lo | (hi << 16);
        }
    }
    __syncthreads();

    const int lane = threadIdx.x & 63;
    const int wave = threadIdx.x >> 6;            // 0..7
    const int s0   = blockIdx.x * 32 + wave * 4;  // 4 consecutive samples per wave

    float h0p[4][10];
    float sv[4], sq[4], lin[4];
    #pragma unroll
    for (int s = 0; s < 4; ++s) {
        sv[s] = 0.f; sq[s] = 0.f; lin[s] = 0.f;
        #pragma unroll
        for (int j = 0; j < 10; ++j) h0p[s][j] = 0.f;
    }

    // R1 skeleton: per-iteration wave-uniform feature/w_table loads + coalesced v gather.
    #pragma unroll 2
    for (int f = 0; f < NF; ++f) {
        int   idx[4];
        float v[4];
        #pragma unroll
        for (int s = 0; s < 4; ++s) {
            idx[s] = feature[(s0 + s) * NF + f];              // wave-uniform address
            v[s]   = v_table[(size_t)idx[s] * NK + lane];     // coalesced 256B gather
            lin[s] += w_table[idx[s]];                        // uniform broadcast
        }
        unsigned u[5];
        #pragma unroll
        for (int jp = 0; jp < 5; ++jp)
            u[jp] = w0_lds[jp * NROW + f * NK + lane];        // conflict-free b32
        #pragma unroll
        for (int s = 0; s < 4; ++s) {
            sv[s] += v[s];
            sq[s]  = fmaf(v[s], v[s], sq[s]);
            #pragma unroll
            for (int jp = 0; jp < 5; ++jp) {
                h0p[s][2 * jp]     = fmaf(v[s], bf_lo(u[jp]), h0p[s][2 * jp]);
                h0p[s][2 * jp + 1] = fmaf(v[s], bf_hi(u[jp]), h0p[s][2 * jp + 1]);
            }
        }
    }

    const float w0v = w0s[0];

    #pragma unroll
    for (int s = 0; s < 4; ++s) {
        float t = fmaf(sv[s], sv[s], -sq[s]);   // s_k^2 - sum_f v_k^2 (per lane k)
        #pragma unroll
        for (int m = 1; m < 64; m <<= 1) {
            t += __shfl_xor(t, m, 64);
            #pragma unroll
            for (int j = 0; j < 10; ++j)
                h0p[s][j] += __shfl_xor(h0p[s][j], m, 64);
        }
        // tiny MLP tail (wave-uniform values, computed redundantly on all lanes)
        float h0v[10];
        #pragma unroll
        for (int j = 0; j < 10; ++j) h0v[j] = fmaxf(h0p[s][j] + b0[j], 0.f);
        float h1[5];
        #pragma unroll
        for (int p = 0; p < 5; ++p) {
            float a = b1[p];
            #pragma unroll
            for (int j = 0; j < 10; ++j) a = fmaf(h0v[j], W1[j * 5 + p], a);
            h1[p] = fmaxf(a, 0.f);
        }
        float h2[3];
        #pragma unroll
        for (int q = 0; q < 3; ++q) {
            float a = b2[q];
            #pragma unroll
            for (int p = 0; p < 5; ++p) a = fmaf(h1[p], W2[p * 3 + q], a);
            h2[q] = fmaxf(a, 0.f);
        }
        float dnn = b3[0];
        #pragma unroll
        for (int q = 0; q < 3; ++q) dnn = fmaf(h2[q], W3[q], dnn);

        if (lane == 0) out[s0 + s] = 0.5f * t + lin[s] + w0v + dnn;
    }
}

extern "C" void kernel_launch(void* const* d_in, const int* in_sizes, int n_in,
                              void* d_out, int out_size, void* d_ws, size_t ws_size,
                              hipStream_t stream) {
    const int*   feature = (const int*)  d_in[0];
    const float* v_table = (const float*)d_in[1];
    const float* w_table = (const float*)d_in[2];
    const float* w0s     = (const float*)d_in[3];
    const float* W0      = (const float*)d_in[4];
    const float* b0      = (const float*)d_in[5];
    const float* W1      = (const float*)d_in[6];
    const float* b1      = (const float*)d_in[7];
    const float* W2      = (const float*)d_in[8];
    const float* b2      = (const float*)d_in[9];
    const float* W3      = (const float*)d_in[10];
    const float* b3      = (const float*)d_in[11];

    deepfm_kernel<<<dim3(512), dim3(512), 0, stream>>>(
        feature, v_table, w_table, w0s, W0, b0, W1, b1, W2, b2, W3, b3,
        (float*)d_out);
}

// Round 6
// 44.494 us; speedup vs baseline: 14.2903x; 1.1801x over previous
//
#include <hip/hip_runtime.h>
#include <hip/hip_bf16.h>

#define NF 39
#define NK 64
#define NROW (NF * NK)   // 2496

__device__ __forceinline__ float bf_lo(unsigned u) { return __uint_as_float(u << 16); }
__device__ __forceinline__ float bf_hi(unsigned u) { return __uint_as_float(u & 0xffff0000u); }

__device__ __forceinline__ unsigned f2bf(float f) {
    unsigned u = __float_as_uint(f);
    return (u + 0x7fffu + ((u >> 16) & 1u)) >> 16;   // RNE
}

__global__ __launch_bounds__(512, 2)
void deepfm_kernel(const int* __restrict__ feature,
                   const float* __restrict__ v_table,
                   const float* __restrict__ w_table,
                   const float* __restrict__ w0s,
                   const float* __restrict__ W0,
                   const float* __restrict__ b0,
                   const float* __restrict__ W1,
                   const float* __restrict__ b1,
                   const float* __restrict__ W2,
                   const float* __restrict__ b2,
                   const float* __restrict__ W3,
                   const float* __restrict__ b3,
                   float* __restrict__ out)
{
    // W0 as packed bf16 pairs, [jp][row]: row = f*64+k. Lane reads 4 consecutive
    // rows (its k-quad) as one ds_read_b128 -> conflict-free (16 distinct 16B
    // addrs spanning all banks 2-way + 3 duplicate groups broadcast).
    __shared__ unsigned w0_lds[5 * NROW];   // 49920 B

    for (int i = threadIdx.x; i < NROW; i += 512) {
        #pragma unroll
        for (int jp = 0; jp < 5; ++jp) {
            unsigned lo = f2bf(W0[i * 10 + 2 * jp]);
            unsigned hi = f2bf(W0[i * 10 + 2 * jp + 1]);
            w0_lds[jp * NROW + i] = lo | (hi << 16);
        }
    }
    __syncthreads();

    const int lane = threadIdx.x & 63;
    const int wave = threadIdx.x >> 6;            // 0..7
    const int s0   = blockIdx.x * 32 + wave * 4;  // 4 samples per wave
    const int sg   = lane >> 4;                   // which sample (0..3)
    const int kq   = lane & 15;                   // k-quad: lane owns k = kq*4..kq*4+3

    const int* fptr = feature + (size_t)(s0 + sg) * NF;   // per-lane, loop-invariant

    float h0p[4][10];                 // [k-slot][j] partial DNN layer-0
    float sv[4], sq[4];
    float lin = 0.f;                  // full per-sample sum, identical within group
    #pragma unroll
    for (int i = 0; i < 4; ++i) {
        sv[i] = 0.f; sq[i] = 0.f;
        #pragma unroll
        for (int j = 0; j < 10; ++j) h0p[i][j] = 0.f;
    }

    #pragma unroll 2
    for (int f = 0; f < NF; ++f) {
        const int idx = fptr[f];                        // 16-lane dup, HW-merged
        lin += w_table[idx];                            // 4B gather, cache-resident
        // one wave-instruction fetches 4 full 256B rows (1KB in flight per instr)
        const float4 v4 = ((const float4*)(v_table + ((size_t)(unsigned)idx << 6)))[kq];
        const float vv[4] = { v4.x, v4.y, v4.z, v4.w };
        #pragma unroll
        for (int i = 0; i < 4; ++i) {
            sv[i] += vv[i];
            sq[i]  = fmaf(vv[i], vv[i], sq[i]);
        }
        #pragma unroll
        for (int jp = 0; jp < 5; ++jp) {
            const uint4 u = *(const uint4*)&w0_lds[jp * NROW + f * NK + kq * 4];
            h0p[0][2*jp]   = fmaf(vv[0], bf_lo(u.x), h0p[0][2*jp]);
            h0p[0][2*jp+1] = fmaf(vv[0], bf_hi(u.x), h0p[0][2*jp+1]);
            h0p[1][2*jp]   = fmaf(vv[1], bf_lo(u.y), h0p[1][2*jp]);
            h0p[1][2*jp+1] = fmaf(vv[1], bf_hi(u.y), h0p[1][2*jp+1]);
            h0p[2][2*jp]   = fmaf(vv[2], bf_lo(u.z), h0p[2][2*jp]);
            h0p[2][2*jp+1] = fmaf(vv[2], bf_hi(u.z), h0p[2][2*jp+1]);
            h0p[3][2*jp]   = fmaf(vv[3], bf_lo(u.w), h0p[3][2*jp]);
            h0p[3][2*jp+1] = fmaf(vv[3], bf_hi(u.w), h0p[3][2*jp+1]);
        }
    }

    // fold k-slots, then 4-step butterfly across the 16-lane group
    float t = 0.f;
    #pragma unroll
    for (int i = 0; i < 4; ++i) t += fmaf(sv[i], sv[i], -sq[i]);
    float hj[10];
    #pragma unroll
    for (int j = 0; j < 10; ++j)
        hj[j] = (h0p[0][j] + h0p[1][j]) + (h0p[2][j] + h0p[3][j]);
    #pragma unroll
    for (int m = 1; m < 16; m <<= 1) {
        t += __shfl_xor(t, m, 64);
        #pragma unroll
        for (int j = 0; j < 10; ++j)
            hj[j] += __shfl_xor(hj[j], m, 64);
    }

    // tiny MLP tail (values uniform within group; computed redundantly)
    const float w0v = w0s[0];
    float h0v[10];
    #pragma unroll
    for (int j = 0; j < 10; ++j) h0v[j] = fmaxf(hj[j] + b0[j], 0.f);
    float h1[5];
    #pragma unroll
    for (int p = 0; p < 5; ++p) {
        float a = b1[p];
        #pragma unroll
        for (int j = 0; j < 10; ++j) a = fmaf(h0v[j], W1[j * 5 + p], a);
        h1[p] = fmaxf(a, 0.f);
    }
    float h2[3];
    #pragma unroll
    for (int q = 0; q < 3; ++q) {
        float a = b2[q];
        #pragma unroll
        for (int p = 0; p < 5; ++p) a = fmaf(h1[p], W2[p * 3 + q], a);
        h2[q] = fmaxf(a, 0.f);
    }
    float dnn = b3[0];
    #pragma unroll
    for (int q = 0; q < 3; ++q) dnn = fmaf(h2[q], W3[q], dnn);

    if (kq == 0) out[s0 + sg] = 0.5f * t + lin + w0v + dnn;
}

extern "C" void kernel_launch(void* const* d_in, const int* in_sizes, int n_in,
                              void* d_out, int out_size, void* d_ws, size_t ws_size,
                              hipStream_t stream) {
    const int*   feature = (const int*)  d_in[0];
    const float* v_table = (const float*)d_in[1];
    const float* w_table = (const float*)d_in[2];
    const float* w0s     = (const float*)d_in[3];
    const float* W0      = (const float*)d_in[4];
    const float* b0      = (const float*)d_in[5];
    const float* W1      = (const float*)d_in[6];
    const float* b1      = (const float*)d_in[7];
    const float* W2      = (const float*)d_in[8];
    const float* b2      = (const float*)d_in[9];
    const float* W3      = (const float*)d_in[10];
    const float* b3      = (const float*)d_in[11];

    deepfm_kernel<<<dim3(512), dim3(512), 0, stream>>>(
        feature, v_table, w_table, w0s, W0, b0, W1, b1, W2, b2, W3, b3,
        (float*)d_out);
}